// Round 9
// baseline (324.554 us; speedup 1.0000x reference)
//
#include <hip/hip_runtime.h>

#define NN 50000

typedef __bf16 bf16x8 __attribute__((ext_vector_type(8)));
typedef float f32x4 __attribute__((ext_vector_type(4)));

__device__ __forceinline__ unsigned short f2bf(float f) {
    unsigned int u = __builtin_bit_cast(unsigned int, f);
    u += 0x7FFF + ((u >> 16) & 1);  // round-to-nearest-even
    return (unsigned short)(u >> 16);
}
__device__ __forceinline__ float bf2f(unsigned short h) {
    unsigned int u = ((unsigned int)h) << 16;
    return __builtin_bit_cast(float, u);
}
__device__ __forceinline__ void gload16(const void* g, void* l) {
    __builtin_amdgcn_global_load_lds(
        (const __attribute__((address_space(1))) unsigned int*)g,
        (__attribute__((address_space(3))) unsigned int*)l, 16, 0, 0);
}
__device__ __forceinline__ void keep(uint4 v) {
    asm volatile("" ::"v"(v.x), "v"(v.y), "v"(v.z), "v"(v.w));
}

// ---------------- edge dtype detection ----------------
__global__ void detect_kernel(const int* __restrict__ ei32, int* __restrict__ flag) {
    __shared__ int red[256];
    int tid = threadIdx.x;
    int o = 0;
    for (int i = tid; i < 4096; i += 256) o |= ei32[2 * i + 1];
    red[tid] = o;
    __syncthreads();
    for (int s = 128; s > 0; s >>= 1) {
        if (tid < s) red[tid] |= red[tid + s];
        __syncthreads();
    }
    if (tid == 0) *flag = (red[0] == 0) ? 1 : 0;
}

__device__ __forceinline__ int load_edge(const void* ei, int is64, long long idx) {
    return is64 ? (int)((const long long*)ei)[idx] : ((const int*)ei)[idx];
}

// ---------------- CSR build ----------------
__global__ void hist_kernel(const void* __restrict__ ei, const int* __restrict__ flag,
                            int* __restrict__ cnt, int E) {
    int e = blockIdx.x * blockDim.x + threadIdx.x;
    if (e >= E) return;
    int is64 = *flag;
    int dst = load_edge(ei, is64, (long long)E + e);
    atomicAdd(&cnt[dst], 1);
}

__global__ void scan_part(const int* __restrict__ cnt, int* __restrict__ bsum, int n) {
    __shared__ int s[256];
    const int tid = threadIdx.x;
    const int i0 = blockIdx.x * 1024 + tid * 4;
    int sum = 0;
#pragma unroll
    for (int j = 0; j < 4; ++j) {
        int i = i0 + j;
        if (i < n) sum += cnt[i];
    }
    s[tid] = sum;
    __syncthreads();
    for (int o = 128; o > 0; o >>= 1) {
        if (tid < o) s[tid] += s[tid + o];
        __syncthreads();
    }
    if (tid == 0) bsum[blockIdx.x] = s[0];
}

__global__ void scan_top(int* __restrict__ bsum, int* __restrict__ off, int nb, int n) {
    const int lane = threadIdx.x & 63;
    int mine = (lane < nb) ? bsum[lane] : 0;
    int v = mine;
#pragma unroll
    for (int o = 1; o < 64; o <<= 1) {
        int t = __shfl_up(v, o, 64);
        if (lane >= o) v += t;
    }
    if (lane < nb) bsum[lane] = v - mine;
    if (lane == 63) off[n] = v;
}

__global__ void scan_fin(const int* __restrict__ cnt, const int* __restrict__ bsum,
                         int* __restrict__ off, int* __restrict__ pos, int n) {
    __shared__ int s[256];
    const int tid = threadIdx.x;
    const int i0 = blockIdx.x * 1024 + tid * 4;
    int v[4];
    int sum = 0;
#pragma unroll
    for (int j = 0; j < 4; ++j) {
        int i = i0 + j;
        v[j] = (i < n) ? cnt[i] : 0;
        sum += v[j];
    }
    s[tid] = sum;
    __syncthreads();
    for (int o = 1; o < 256; o <<= 1) {
        int t = 0;
        if (tid >= o) t = s[tid - o];
        __syncthreads();
        s[tid] += t;
        __syncthreads();
    }
    int run = bsum[blockIdx.x] + s[tid] - sum;
#pragma unroll
    for (int j = 0; j < 4; ++j) {
        int i = i0 + j;
        if (i < n) {
            off[i] = run;
            pos[i] = run;
            run += v[j];
        }
    }
}

__global__ void fill_kernel(const void* __restrict__ ei, const int* __restrict__ flag,
                            int* __restrict__ pos, int* __restrict__ adj, int E) {
    int e = blockIdx.x * blockDim.x + threadIdx.x;
    if (e >= E) return;
    int is64 = *flag;
    int src = load_edge(ei, is64, e);
    int dst = load_edge(ei, is64, (long long)E + e);
    int p = atomicAdd(&pos[dst], 1);
    adj[p] = src;
}

// ---------------- f32 -> bf16 convert ----------------
__global__ void cvt_bf16(const float* __restrict__ in, unsigned short* __restrict__ out, int n4) {
    int i = blockIdx.x * blockDim.x + threadIdx.x;
    if (i >= n4) return;
    float4 v = ((const float4*)in)[i];
    uint2 o;
    o.x = (unsigned int)f2bf(v.x) | ((unsigned int)f2bf(v.y) << 16);
    o.y = (unsigned int)f2bf(v.z) | ((unsigned int)f2bf(v.w) << 16);
    ((uint2*)out)[i] = o;
}

// ---------------- weight prep: Wt[c][k] = bf16([Wl; Wr][k][c]) ----------------
__global__ void prep_w(const float* __restrict__ Wl, const float* __restrict__ Wr,
                       unsigned short* __restrict__ Wt, int KH) {
    int c = blockIdx.x;
    int KC = 2 * KH;
    for (int k = threadIdx.x; k < KC; k += blockDim.x) {
        float v = (k < KH) ? Wl[(size_t)k * 256 + c] : Wr[(size_t)(k - KH) * 256 + c];
        Wt[(size_t)c * KC + k] = f2bf(v);
    }
}

// ---------------- mean aggregation (MLP=4 unroll) ----------------
template <int VPL>
__global__ void agg_bf(const unsigned short* __restrict__ feat, const int* __restrict__ off,
                       const int* __restrict__ adj, unsigned short* __restrict__ out, int n) {
    int node = blockIdx.x * 4 + (threadIdx.x >> 6);
    if (node >= n) return;
    const int lane = threadIdx.x & 63;
    constexpr int F = 64 * VPL;
    const int s = off[node], e = off[node + 1];

    float a0[VPL] = {}, a1[VPL] = {}, a2[VPL] = {}, a3[VPL] = {};

    auto addrow = [&](float* acc, int src) {
        const unsigned short* p = feat + (size_t)src * F + lane * VPL;
        if constexpr (VPL == 2) {
            unsigned int v = *(const unsigned int*)p;
            acc[0] += bf2f((unsigned short)(v & 0xffff));
            acc[1] += bf2f((unsigned short)(v >> 16));
        } else {
            uint2 v = *(const uint2*)p;
            acc[0] += bf2f((unsigned short)(v.x & 0xffff));
            acc[1] += bf2f((unsigned short)(v.x >> 16));
            acc[2] += bf2f((unsigned short)(v.y & 0xffff));
            acc[3] += bf2f((unsigned short)(v.y >> 16));
        }
    };

    int j = s;
    for (; j + 4 <= e; j += 4) {
        int i0 = adj[j], i1 = adj[j + 1], i2 = adj[j + 2], i3 = adj[j + 3];
        addrow(a0, i0);
        addrow(a1, i1);
        addrow(a2, i2);
        addrow(a3, i3);
    }
    {
        int rem = e - j;
        if (rem > 0) addrow(a0, adj[j]);
        if (rem > 1) addrow(a1, adj[j + 1]);
        if (rem > 2) addrow(a2, adj[j + 2]);
    }

    int deg = e - s;
    float inv = 1.0f / (float)(deg > 0 ? deg : 1);
#pragma unroll
    for (int k = 0; k < VPL; ++k) a0[k] = (a0[k] + a1[k] + a2[k] + a3[k]) * inv;

    if constexpr (VPL == 2) {
        unsigned int o = (unsigned int)f2bf(a0[0]) | ((unsigned int)f2bf(a0[1]) << 16);
        *(unsigned int*)(out + (size_t)node * F + lane * 2) = o;
    } else {
        uint2 o;
        o.x = (unsigned int)f2bf(a0[0]) | ((unsigned int)f2bf(a0[1]) << 16);
        o.y = (unsigned int)f2bf(a0[2]) | ((unsigned int)f2bf(a0[3]) << 16);
        *(uint2*)(out + (size_t)node * F + lane * 4) = o;
    }
}

// ---------------- fused SAGE MFMA GEMM (R4 structure: best known, 48.7us L1) ----------
template <int KH, bool L0>
__global__ __launch_bounds__(256, 2) void sage_mfma(
    const unsigned short* __restrict__ Aagg, const unsigned short* __restrict__ Axin,
    const unsigned short* __restrict__ Wt, const float* __restrict__ bl,
    const float* __restrict__ bng, const float* __restrict__ bnb,
    const float* __restrict__ bnm, const float* __restrict__ bnv,
    unsigned short* __restrict__ hout, float* __restrict__ fout, int n) {
    constexpr int KC = 2 * KH;
    constexpr int NSTEP = KC / 32;
    __shared__ __align__(16) unsigned short a_sh[2][4][64][8];
    __shared__ float red[4][64];
    __shared__ float inv_sh[64];

    const int tid = threadIdx.x;
    const int w = tid >> 6;
    const int l = tid & 63;
    const int g = l >> 4;
    const int li = l & 15;
    const int row0 = blockIdx.x * 64;
    int srow = row0 + l;
    if (srow >= n) srow = n - 1;

    f32x4 acc[4][4];
#pragma unroll
    for (int m = 0; m < 4; ++m)
#pragma unroll
        for (int nn = 0; nn < 4; ++nn) acc[m][nn] = (f32x4)(0.0f);

    auto stage = [&](int buf, int t) {
        const int k0 = t * 32;
        const unsigned short* srcm = (k0 < KH) ? Aagg : Axin;
        const int kk = (k0 < KH) ? k0 : k0 - KH;
        const unsigned short* gp = srcm + (size_t)srow * KH + kk + w * 8;
        gload16(gp, &a_sh[buf][w][0][0]);
    };

    stage(0, 0);
    __syncthreads();

    int cur = 0;
    for (int ks = 0; ks < NSTEP; ++ks) {
        if (ks + 1 < NSTEP) stage(cur ^ 1, ks + 1);
        const int k0 = ks * 32;
        bf16x8 bfr[4];
#pragma unroll
        for (int nn = 0; nn < 4; ++nn) {
            const unsigned short* bp = Wt + (size_t)(w * 64 + nn * 16 + li) * KC + k0 + 8 * g;
            bfr[nn] = __builtin_bit_cast(bf16x8, *(const uint4*)bp);
        }
        bf16x8 afr[4];
#pragma unroll
        for (int m = 0; m < 4; ++m)
            afr[m] = __builtin_bit_cast(bf16x8, *(const uint4*)&a_sh[cur][g][16 * m + li][0]);
#pragma unroll
        for (int nn = 0; nn < 4; ++nn)
#pragma unroll
            for (int m = 0; m < 4; ++m)
                acc[m][nn] = __builtin_amdgcn_mfma_f32_16x16x32_bf16(afr[m], bfr[nn], acc[m][nn], 0, 0, 0);
        __syncthreads();
        cur ^= 1;
    }

    float bv[4];
#pragma unroll
    for (int nn = 0; nn < 4; ++nn) bv[nn] = bl[w * 64 + nn * 16 + li];
#pragma unroll
    for (int m = 0; m < 4; ++m)
#pragma unroll
        for (int nn = 0; nn < 4; ++nn)
#pragma unroll
            for (int r = 0; r < 4; ++r) acc[m][nn][r] += bv[nn];

    float ssp[4][4];
#pragma unroll
    for (int m = 0; m < 4; ++m)
#pragma unroll
        for (int r = 0; r < 4; ++r) {
            float s = 0.f;
#pragma unroll
            for (int nn = 0; nn < 4; ++nn) s += acc[m][nn][r] * acc[m][nn][r];
#pragma unroll
            for (int mk = 1; mk < 16; mk <<= 1) s += __shfl_xor(s, mk, 64);
            ssp[m][r] = s;
        }
    if (li == 0) {
#pragma unroll
        for (int m = 0; m < 4; ++m)
#pragma unroll
            for (int r = 0; r < 4; ++r) red[w][16 * m + 4 * g + r] = ssp[m][r];
    }
    __syncthreads();
    if (tid < 64) {
        float tot = red[0][tid] + red[1][tid] + red[2][tid] + red[3][tid];
        inv_sh[tid] = 1.0f / fmaxf(sqrtf(tot), 1e-12f);
    }
    __syncthreads();

    float sc[4], sh[4];
    if (L0) {
#pragma unroll
        for (int nn = 0; nn < 4; ++nn) {
            int c = w * 64 + nn * 16 + li;
            float s = bng[c] * rsqrtf(bnv[c] + 1e-5f);
            sc[nn] = s;
            sh[nn] = bnb[c] - bnm[c] * s;
        }
    }
#pragma unroll
    for (int m = 0; m < 4; ++m) {
#pragma unroll
        for (int r = 0; r < 4; ++r) {
            int rl = 16 * m + 4 * g + r;
            int row = row0 + rl;
            if (row < n) {
                float inv = inv_sh[rl];
#pragma unroll
                for (int nn = 0; nn < 4; ++nn) {
                    int c = w * 64 + nn * 16 + li;
                    float v = acc[m][nn][r] * inv;
                    if (L0) {
                        v = fmaxf(v * sc[nn] + sh[nn], 0.f);
                        hout[(size_t)row * 256 + c] = f2bf(v);
                    } else {
                        fout[(size_t)row * 256 + c] = v;
                    }
                }
            }
        }
    }
}

// ================= ABLATION PROBES (L1 config: KH=256, NSTEP=16) =================
// p_load: exact R4 staging + barriers + B loads + ds_reads; MFMA replaced by keep().
__global__ __launch_bounds__(256, 2) void p_load(
    const unsigned short* __restrict__ Aagg, const unsigned short* __restrict__ Axin,
    const unsigned short* __restrict__ Wt, unsigned short* __restrict__ outp, int n) {
    constexpr int KH = 256, KC = 512, NSTEP = 16;
    __shared__ __align__(16) unsigned short a_sh[2][4][64][8];
    const int tid = threadIdx.x;
    const int w = tid >> 6;
    const int l = tid & 63;
    const int g = l >> 4;
    const int li = l & 15;
    const int row0 = blockIdx.x * 64;
    int srow = row0 + l;
    if (srow >= n) srow = n - 1;

    auto stage = [&](int buf, int t) {
        const int k0 = t * 32;
        const unsigned short* srcm = (k0 < KH) ? Aagg : Axin;
        const int kk = (k0 < KH) ? k0 : k0 - KH;
        const unsigned short* gp = srcm + (size_t)srow * KH + kk + w * 8;
        gload16(gp, &a_sh[buf][w][0][0]);
    };

    stage(0, 0);
    __syncthreads();
    int cur = 0;
    for (int ks = 0; ks < NSTEP; ++ks) {
        if (ks + 1 < NSTEP) stage(cur ^ 1, ks + 1);
        const int k0 = ks * 32;
#pragma unroll
        for (int nn = 0; nn < 4; ++nn) {
            const unsigned short* bp = Wt + (size_t)(w * 64 + nn * 16 + li) * KC + k0 + 8 * g;
            keep(*(const uint4*)bp);
        }
#pragma unroll
        for (int m = 0; m < 4; ++m) keep(*(const uint4*)&a_sh[cur][g][16 * m + li][0]);
        __syncthreads();
        cur ^= 1;
    }
    outp[(size_t)blockIdx.x * 256 + tid] = (unsigned short)tid;
}

// shared epilogue for p_comp / p_epi (mirrors real L1 epilogue incl. f32 stores)
__device__ __forceinline__ void probe_epilogue(f32x4 (&acc)[4][4], float* fout, int n,
                                               float (*red)[64], float* inv_sh) {
    const int tid = threadIdx.x;
    const int w = tid >> 6;
    const int l = tid & 63;
    const int g = l >> 4;
    const int li = l & 15;
    const int row0 = blockIdx.x * 64;
    float ssp[4][4];
#pragma unroll
    for (int m = 0; m < 4; ++m)
#pragma unroll
        for (int r = 0; r < 4; ++r) {
            float s = 0.f;
#pragma unroll
            for (int nn = 0; nn < 4; ++nn) s += acc[m][nn][r] * acc[m][nn][r];
#pragma unroll
            for (int mk = 1; mk < 16; mk <<= 1) s += __shfl_xor(s, mk, 64);
            ssp[m][r] = s;
        }
    if (li == 0) {
#pragma unroll
        for (int m = 0; m < 4; ++m)
#pragma unroll
            for (int r = 0; r < 4; ++r) red[w][16 * m + 4 * g + r] = ssp[m][r];
    }
    __syncthreads();
    if (tid < 64) {
        float tot = red[0][tid] + red[1][tid] + red[2][tid] + red[3][tid];
        inv_sh[tid] = 1.0f / fmaxf(sqrtf(tot), 1e-12f);
    }
    __syncthreads();
#pragma unroll
    for (int m = 0; m < 4; ++m) {
#pragma unroll
        for (int r = 0; r < 4; ++r) {
            int rl = 16 * m + 4 * g + r;
            int row = row0 + rl;
            if (row < n) {
                float inv = inv_sh[rl];
#pragma unroll
                for (int nn = 0; nn < 4; ++nn) {
                    int c = w * 64 + nn * 16 + li;
                    fout[(size_t)row * 256 + c] = acc[m][nn][r] * inv;
                }
            }
        }
    }
}

// p_comp: hash fragments (no global loads), full 16-step MFMA chain + epilogue + stores.
__global__ __launch_bounds__(256, 2) void p_comp(float* __restrict__ fout, int n) {
    __shared__ float red[4][64];
    __shared__ float inv_sh[64];
    const int tid = threadIdx.x;
    unsigned seed = tid * 2654435761u ^ (blockIdx.x * 40503u + 0x9E3779B9u);
    f32x4 acc[4][4];
#pragma unroll
    for (int m = 0; m < 4; ++m)
#pragma unroll
        for (int nn = 0; nn < 4; ++nn) acc[m][nn] = (f32x4)(0.0f);
#pragma unroll
    for (int ks = 0; ks < 16; ++ks) {
        unsigned s0 = seed ^ (unsigned)(ks * 0x85EBCA6B);
        bf16x8 afr[4], bfr[4];
#pragma unroll
        for (int m = 0; m < 4; ++m) {
            uint4 u = make_uint4(s0 + m, s0 ^ (m * 77u), s0 + m * 131u, s0 ^ (m * 9u + 5u));
            afr[m] = __builtin_bit_cast(bf16x8, u);
        }
#pragma unroll
        for (int nn = 0; nn < 4; ++nn) {
            uint4 u = make_uint4(s0 ^ (nn * 313u), s0 + nn * 57u, s0 ^ (nn * 3u + 11u), s0 + nn * 201u);
            bfr[nn] = __builtin_bit_cast(bf16x8, u);
        }
#pragma unroll
        for (int nn = 0; nn < 4; ++nn)
#pragma unroll
            for (int m = 0; m < 4; ++m)
                acc[m][nn] = __builtin_amdgcn_mfma_f32_16x16x32_bf16(afr[m], bfr[nn], acc[m][nn], 0, 0, 0);
    }
    probe_epilogue(acc, fout, n, red, inv_sh);
}

// p_epi: hash accumulators, epilogue + stores only.
__global__ __launch_bounds__(256, 2) void p_epi(float* __restrict__ fout, int n) {
    __shared__ float red[4][64];
    __shared__ float inv_sh[64];
    const int tid = threadIdx.x;
    unsigned seed = tid * 1664525u + blockIdx.x * 1013904223u;
    f32x4 acc[4][4];
#pragma unroll
    for (int m = 0; m < 4; ++m)
#pragma unroll
        for (int nn = 0; nn < 4; ++nn)
#pragma unroll
            for (int r = 0; r < 4; ++r)
                acc[m][nn][r] = (float)((seed >> ((m + nn + r) & 15)) & 0xff) * 0.01f + 0.5f;
    probe_epilogue(acc, fout, n, red, inv_sh);
}

// ---------------- launch ----------------
extern "C" void kernel_launch(void* const* d_in, const int* in_sizes, int n_in,
                              void* d_out, int out_size, void* d_ws, size_t ws_size,
                              hipStream_t stream) {
    const float* x   = (const float*)d_in[0];
    const void*  ei  = d_in[1];
    const float* Wl0 = (const float*)d_in[2];
    const float* bl0 = (const float*)d_in[3];
    const float* Wr0 = (const float*)d_in[4];
    const float* Wl1 = (const float*)d_in[5];
    const float* bl1 = (const float*)d_in[6];
    const float* Wr1 = (const float*)d_in[7];
    const float* bng = (const float*)d_in[8];
    const float* bnb = (const float*)d_in[9];
    const float* bnm = (const float*)d_in[10];
    const float* bnv = (const float*)d_in[11];
    float* out = (float*)d_out;

    const int N = NN;
    const int E = in_sizes[1] / 2;
    const int NB = (N + 1023) / 1024;

    char* wsp = (char*)d_ws;
    size_t o = 0;
    auto carve = [&](size_t bytes) {
        void* p = wsp + o;
        o = (o + bytes + 255) & ~(size_t)255;
        return p;
    };
    int* flag = (int*)carve(4);
    int* cnt  = (int*)carve((size_t)N * 4);
    int* off  = (int*)carve((size_t)(N + 1) * 4);
    int* pos  = (int*)carve((size_t)N * 4);
    int* bsum = (int*)carve((size_t)NB * 4);
    int* adj  = (int*)carve((size_t)E * 4);
    unsigned short* xbf  = (unsigned short*)carve((size_t)N * 128 * 2);
    unsigned short* agg0 = (unsigned short*)carve((size_t)N * 128 * 2);
    unsigned short* agg1 = xbf;  // reuse xbf+agg0 region (dead after layer 0)
    unsigned short* hbf  = (unsigned short*)carve((size_t)N * 256 * 2);
    unsigned short* Wt0  = (unsigned short*)carve((size_t)256 * 256 * 2);
    unsigned short* Wt1  = (unsigned short*)carve((size_t)256 * 512 * 2);
    // probe scratch: xbf..hbf span = 12.8+12.8+25.6 = 51.2MB, all fully rewritten
    // (cvt_bf16 / agg_bf<2> / sage_mfma L0) before any read on every call.
    float* pscr = (float*)xbf;

    hipMemsetAsync(d_ws, 0, 256 + (size_t)N * 4, stream);

    detect_kernel<<<1, 256, 0, stream>>>((const int*)ei, flag);
    hist_kernel<<<(E + 255) / 256, 256, 0, stream>>>(ei, flag, cnt, E);
    scan_part<<<NB, 256, 0, stream>>>(cnt, bsum, N);
    scan_top<<<1, 64, 0, stream>>>(bsum, off, NB, N);
    scan_fin<<<NB, 256, 0, stream>>>(cnt, bsum, off, pos, N);
    fill_kernel<<<(E + 255) / 256, 256, 0, stream>>>(ei, flag, pos, adj, E);

    cvt_bf16<<<(N * 128 / 4 + 255) / 256, 256, 0, stream>>>(x, xbf, N * 128 / 4);
    prep_w<<<256, 256, 0, stream>>>(Wl0, Wr0, Wt0, 128);
    prep_w<<<256, 256, 0, stream>>>(Wl1, Wr1, Wt1, 256);

    agg_bf<2><<<(N + 3) / 4, 256, 0, stream>>>(xbf, off, adj, agg0, N);
    sage_mfma<128, true><<<(N + 63) / 64, 256, 0, stream>>>(
        agg0, xbf, Wt0, bl0, bng, bnb, bnm, bnv, hbf, nullptr, N);

    agg_bf<4><<<(N + 3) / 4, 256, 0, stream>>>(hbf, off, adj, agg1, N);
    sage_mfma<256, false><<<(N + 63) / 64, 256, 0, stream>>>(
        agg1, hbf, Wt1, bl1, bng, bnb, bnm, bnv, nullptr, out, N);

    // -------- ablation probes (after real pipeline; write only to ws scratch) --------
    const int GB = (N + 63) / 64;  // 782, same grid as real L1
    p_load<<<GB, 256, 0, stream>>>(agg1, hbf, Wt1, (unsigned short*)adj, N);
    p_comp<<<GB, 256, 0, stream>>>(pscr, N);
    p_epi<<<GB, 256, 0, stream>>>(pscr, N);
}

// Round 10
// 247.412 us; speedup vs baseline: 1.3118x; 1.3118x over previous
//
#include <hip/hip_runtime.h>

#define NN 50000

typedef __bf16 bf16x8 __attribute__((ext_vector_type(8)));
typedef float f32x4 __attribute__((ext_vector_type(4)));

__device__ __forceinline__ unsigned short f2bf(float f) {
    unsigned int u = __builtin_bit_cast(unsigned int, f);
    u += 0x7FFF + ((u >> 16) & 1);  // round-to-nearest-even
    return (unsigned short)(u >> 16);
}
__device__ __forceinline__ float bf2f(unsigned short h) {
    unsigned int u = ((unsigned int)h) << 16;
    return __builtin_bit_cast(float, u);
}
__device__ __forceinline__ void gload16(const void* g, void* l) {
    __builtin_amdgcn_global_load_lds(
        (const __attribute__((address_space(1))) unsigned int*)g,
        (__attribute__((address_space(3))) unsigned int*)l, 16, 0, 0);
}

// ---------------- edge dtype detection ----------------
__global__ void detect_kernel(const int* __restrict__ ei32, int* __restrict__ flag) {
    __shared__ int red[256];
    int tid = threadIdx.x;
    int o = 0;
    for (int i = tid; i < 4096; i += 256) o |= ei32[2 * i + 1];
    red[tid] = o;
    __syncthreads();
    for (int s = 128; s > 0; s >>= 1) {
        if (tid < s) red[tid] |= red[tid + s];
        __syncthreads();
    }
    if (tid == 0) *flag = (red[0] == 0) ? 1 : 0;
}

__device__ __forceinline__ int load_edge(const void* ei, int is64, long long idx) {
    return is64 ? (int)((const long long*)ei)[idx] : ((const int*)ei)[idx];
}

// ---------------- CSR build ----------------
__global__ void hist_kernel(const void* __restrict__ ei, const int* __restrict__ flag,
                            int* __restrict__ cnt, int E) {
    int e = blockIdx.x * blockDim.x + threadIdx.x;
    if (e >= E) return;
    int is64 = *flag;
    int dst = load_edge(ei, is64, (long long)E + e);
    atomicAdd(&cnt[dst], 1);
}

__global__ void scan_part(const int* __restrict__ cnt, int* __restrict__ bsum, int n) {
    __shared__ int s[256];
    const int tid = threadIdx.x;
    const int i0 = blockIdx.x * 1024 + tid * 4;
    int sum = 0;
#pragma unroll
    for (int j = 0; j < 4; ++j) {
        int i = i0 + j;
        if (i < n) sum += cnt[i];
    }
    s[tid] = sum;
    __syncthreads();
    for (int o = 128; o > 0; o >>= 1) {
        if (tid < o) s[tid] += s[tid + o];
        __syncthreads();
    }
    if (tid == 0) bsum[blockIdx.x] = s[0];
}

__global__ void scan_top(int* __restrict__ bsum, int* __restrict__ off, int nb, int n) {
    const int lane = threadIdx.x & 63;
    int mine = (lane < nb) ? bsum[lane] : 0;
    int v = mine;
#pragma unroll
    for (int o = 1; o < 64; o <<= 1) {
        int t = __shfl_up(v, o, 64);
        if (lane >= o) v += t;
    }
    if (lane < nb) bsum[lane] = v - mine;
    if (lane == 63) off[n] = v;
}

__global__ void scan_fin(const int* __restrict__ cnt, const int* __restrict__ bsum,
                         int* __restrict__ off, int* __restrict__ pos, int n) {
    __shared__ int s[256];
    const int tid = threadIdx.x;
    const int i0 = blockIdx.x * 1024 + tid * 4;
    int v[4];
    int sum = 0;
#pragma unroll
    for (int j = 0; j < 4; ++j) {
        int i = i0 + j;
        v[j] = (i < n) ? cnt[i] : 0;
        sum += v[j];
    }
    s[tid] = sum;
    __syncthreads();
    for (int o = 1; o < 256; o <<= 1) {
        int t = 0;
        if (tid >= o) t = s[tid - o];
        __syncthreads();
        s[tid] += t;
        __syncthreads();
    }
    int run = bsum[blockIdx.x] + s[tid] - sum;
#pragma unroll
    for (int j = 0; j < 4; ++j) {
        int i = i0 + j;
        if (i < n) {
            off[i] = run;
            pos[i] = run;
            run += v[j];
        }
    }
}

__global__ void fill_kernel(const void* __restrict__ ei, const int* __restrict__ flag,
                            int* __restrict__ pos, int* __restrict__ adj, int E) {
    int e = blockIdx.x * blockDim.x + threadIdx.x;
    if (e >= E) return;
    int is64 = *flag;
    int src = load_edge(ei, is64, e);
    int dst = load_edge(ei, is64, (long long)E + e);
    int p = atomicAdd(&pos[dst], 1);
    adj[p] = src;
}

// ---------------- f32 -> bf16 convert ----------------
__global__ void cvt_bf16(const float* __restrict__ in, unsigned short* __restrict__ out, int n4) {
    int i = blockIdx.x * blockDim.x + threadIdx.x;
    if (i >= n4) return;
    float4 v = ((const float4*)in)[i];
    uint2 o;
    o.x = (unsigned int)f2bf(v.x) | ((unsigned int)f2bf(v.y) << 16);
    o.y = (unsigned int)f2bf(v.z) | ((unsigned int)f2bf(v.w) << 16);
    ((uint2*)out)[i] = o;
}

// ---------------- weight prep: Wt[c][k] = bf16([Wl; Wr][k][c]) ----------------
__global__ void prep_w(const float* __restrict__ Wl, const float* __restrict__ Wr,
                       unsigned short* __restrict__ Wt, int KH) {
    int c = blockIdx.x;
    int KC = 2 * KH;
    for (int k = threadIdx.x; k < KC; k += blockDim.x) {
        float v = (k < KH) ? Wl[(size_t)k * 256 + c] : Wr[(size_t)(k - KH) * 256 + c];
        Wt[(size_t)c * KC + k] = f2bf(v);
    }
}

// ---------------- mean aggregation (MLP=4 unroll) ----------------
template <int VPL>
__global__ void agg_bf(const unsigned short* __restrict__ feat, const int* __restrict__ off,
                       const int* __restrict__ adj, unsigned short* __restrict__ out, int n) {
    int node = blockIdx.x * 4 + (threadIdx.x >> 6);
    if (node >= n) return;
    const int lane = threadIdx.x & 63;
    constexpr int F = 64 * VPL;
    const int s = off[node], e = off[node + 1];

    float a0[VPL] = {}, a1[VPL] = {}, a2[VPL] = {}, a3[VPL] = {};

    auto addrow = [&](float* acc, int src) {
        const unsigned short* p = feat + (size_t)src * F + lane * VPL;
        if constexpr (VPL == 2) {
            unsigned int v = *(const unsigned int*)p;
            acc[0] += bf2f((unsigned short)(v & 0xffff));
            acc[1] += bf2f((unsigned short)(v >> 16));
        } else {
            uint2 v = *(const uint2*)p;
            acc[0] += bf2f((unsigned short)(v.x & 0xffff));
            acc[1] += bf2f((unsigned short)(v.x >> 16));
            acc[2] += bf2f((unsigned short)(v.y & 0xffff));
            acc[3] += bf2f((unsigned short)(v.y >> 16));
        }
    };

    int j = s;
    for (; j + 4 <= e; j += 4) {
        int i0 = adj[j], i1 = adj[j + 1], i2 = adj[j + 2], i3 = adj[j + 3];
        addrow(a0, i0);
        addrow(a1, i1);
        addrow(a2, i2);
        addrow(a3, i3);
    }
    {
        int rem = e - j;
        if (rem > 0) addrow(a0, adj[j]);
        if (rem > 1) addrow(a1, adj[j + 1]);
        if (rem > 2) addrow(a2, adj[j + 2]);
    }

    int deg = e - s;
    float inv = 1.0f / (float)(deg > 0 ? deg : 1);
#pragma unroll
    for (int k = 0; k < VPL; ++k) a0[k] = (a0[k] + a1[k] + a2[k] + a3[k]) * inv;

    if constexpr (VPL == 2) {
        unsigned int o = (unsigned int)f2bf(a0[0]) | ((unsigned int)f2bf(a0[1]) << 16);
        *(unsigned int*)(out + (size_t)node * F + lane * 2) = o;
    } else {
        uint2 o;
        o.x = (unsigned int)f2bf(a0[0]) | ((unsigned int)f2bf(a0[1]) << 16);
        o.y = (unsigned int)f2bf(a0[2]) | ((unsigned int)f2bf(a0[3]) << 16);
        *(uint2*)(out + (size_t)node * F + lane * 4) = o;
    }
}

// ---------------- fused SAGE MFMA GEMM (R4 structure, NO launch_bounds) ----------
// The only change vs R4/R9: no __launch_bounds__ — all prior variants with
// __launch_bounds__(256,{2,4}) pinned at ~2-4 waves/SIMD regardless of LDS/VGPR
// headroom (R8: 1.5KB LDS, 76 VGPR, still 21% occupancy), which starves the CU of
// in-flight memory ops and explains the universal ~7% MfmaUtil.
template <int KH, bool L0>
__global__ void sage_mfma(
    const unsigned short* __restrict__ Aagg, const unsigned short* __restrict__ Axin,
    const unsigned short* __restrict__ Wt, const float* __restrict__ bl,
    const float* __restrict__ bng, const float* __restrict__ bnb,
    const float* __restrict__ bnm, const float* __restrict__ bnv,
    unsigned short* __restrict__ hout, float* __restrict__ fout, int n) {
    constexpr int KC = 2 * KH;
    constexpr int NSTEP = KC / 32;
    __shared__ __align__(16) unsigned short a_sh[2][4][64][8];
    __shared__ float red[4][64];
    __shared__ float inv_sh[64];

    const int tid = threadIdx.x;
    const int w = tid >> 6;
    const int l = tid & 63;
    const int g = l >> 4;
    const int li = l & 15;
    const int row0 = blockIdx.x * 64;
    int srow = row0 + l;
    if (srow >= n) srow = n - 1;

    f32x4 acc[4][4];
#pragma unroll
    for (int m = 0; m < 4; ++m)
#pragma unroll
        for (int nn = 0; nn < 4; ++nn) acc[m][nn] = (f32x4)(0.0f);

    auto stage = [&](int buf, int t) {
        const int k0 = t * 32;
        const unsigned short* srcm = (k0 < KH) ? Aagg : Axin;
        const int kk = (k0 < KH) ? k0 : k0 - KH;
        const unsigned short* gp = srcm + (size_t)srow * KH + kk + w * 8;
        gload16(gp, &a_sh[buf][w][0][0]);
    };

    stage(0, 0);
    __syncthreads();

    int cur = 0;
    for (int ks = 0; ks < NSTEP; ++ks) {
        if (ks + 1 < NSTEP) stage(cur ^ 1, ks + 1);
        const int k0 = ks * 32;
        bf16x8 bfr[4];
#pragma unroll
        for (int nn = 0; nn < 4; ++nn) {
            const unsigned short* bp = Wt + (size_t)(w * 64 + nn * 16 + li) * KC + k0 + 8 * g;
            bfr[nn] = __builtin_bit_cast(bf16x8, *(const uint4*)bp);
        }
        bf16x8 afr[4];
#pragma unroll
        for (int m = 0; m < 4; ++m)
            afr[m] = __builtin_bit_cast(bf16x8, *(const uint4*)&a_sh[cur][g][16 * m + li][0]);
#pragma unroll
        for (int nn = 0; nn < 4; ++nn)
#pragma unroll
            for (int m = 0; m < 4; ++m)
                acc[m][nn] = __builtin_amdgcn_mfma_f32_16x16x32_bf16(afr[m], bfr[nn], acc[m][nn], 0, 0, 0);
        __syncthreads();
        cur ^= 1;
    }

    float bv[4];
#pragma unroll
    for (int nn = 0; nn < 4; ++nn) bv[nn] = bl[w * 64 + nn * 16 + li];
#pragma unroll
    for (int m = 0; m < 4; ++m)
#pragma unroll
        for (int nn = 0; nn < 4; ++nn)
#pragma unroll
            for (int r = 0; r < 4; ++r) acc[m][nn][r] += bv[nn];

    float ssp[4][4];
#pragma unroll
    for (int m = 0; m < 4; ++m)
#pragma unroll
        for (int r = 0; r < 4; ++r) {
            float s = 0.f;
#pragma unroll
            for (int nn = 0; nn < 4; ++nn) s += acc[m][nn][r] * acc[m][nn][r];
#pragma unroll
            for (int mk = 1; mk < 16; mk <<= 1) s += __shfl_xor(s, mk, 64);
            ssp[m][r] = s;
        }
    if (li == 0) {
#pragma unroll
        for (int m = 0; m < 4; ++m)
#pragma unroll
            for (int r = 0; r < 4; ++r) red[w][16 * m + 4 * g + r] = ssp[m][r];
    }
    __syncthreads();
    if (tid < 64) {
        float tot = red[0][tid] + red[1][tid] + red[2][tid] + red[3][tid];
        inv_sh[tid] = 1.0f / fmaxf(sqrtf(tot), 1e-12f);
    }
    __syncthreads();

    float sc[4], sh[4];
    if (L0) {
#pragma unroll
        for (int nn = 0; nn < 4; ++nn) {
            int c = w * 64 + nn * 16 + li;
            float s = bng[c] * rsqrtf(bnv[c] + 1e-5f);
            sc[nn] = s;
            sh[nn] = bnb[c] - bnm[c] * s;
        }
    }
#pragma unroll
    for (int m = 0; m < 4; ++m) {
#pragma unroll
        for (int r = 0; r < 4; ++r) {
            int rl = 16 * m + 4 * g + r;
            int row = row0 + rl;
            if (row < n) {
                float inv = inv_sh[rl];
#pragma unroll
                for (int nn = 0; nn < 4; ++nn) {
                    int c = w * 64 + nn * 16 + li;
                    float v = acc[m][nn][r] * inv;
                    if (L0) {
                        v = fmaxf(v * sc[nn] + sh[nn], 0.f);
                        hout[(size_t)row * 256 + c] = f2bf(v);
                    } else {
                        fout[(size_t)row * 256 + c] = v;
                    }
                }
            }
        }
    }
}

// ---------------- launch ----------------
extern "C" void kernel_launch(void* const* d_in, const int* in_sizes, int n_in,
                              void* d_out, int out_size, void* d_ws, size_t ws_size,
                              hipStream_t stream) {
    const float* x   = (const float*)d_in[0];
    const void*  ei  = d_in[1];
    const float* Wl0 = (const float*)d_in[2];
    const float* bl0 = (const float*)d_in[3];
    const float* Wr0 = (const float*)d_in[4];
    const float* Wl1 = (const float*)d_in[5];
    const float* bl1 = (const float*)d_in[6];
    const float* Wr1 = (const float*)d_in[7];
    const float* bng = (const float*)d_in[8];
    const float* bnb = (const float*)d_in[9];
    const float* bnm = (const float*)d_in[10];
    const float* bnv = (const float*)d_in[11];
    float* out = (float*)d_out;

    const int N = NN;
    const int E = in_sizes[1] / 2;
    const int NB = (N + 1023) / 1024;

    char* wsp = (char*)d_ws;
    size_t o = 0;
    auto carve = [&](size_t bytes) {
        void* p = wsp + o;
        o = (o + bytes + 255) & ~(size_t)255;
        return p;
    };
    int* flag = (int*)carve(4);
    int* cnt  = (int*)carve((size_t)N * 4);
    int* off  = (int*)carve((size_t)(N + 1) * 4);
    int* pos  = (int*)carve((size_t)N * 4);
    int* bsum = (int*)carve((size_t)NB * 4);
    int* adj  = (int*)carve((size_t)E * 4);
    unsigned short* xbf  = (unsigned short*)carve((size_t)N * 128 * 2);
    unsigned short* agg0 = (unsigned short*)carve((size_t)N * 128 * 2);
    unsigned short* agg1 = xbf;  // reuse xbf region (dead after layer 0)
    unsigned short* hbf  = (unsigned short*)carve((size_t)N * 256 * 2);
    unsigned short* Wt0  = (unsigned short*)carve((size_t)256 * 256 * 2);
    unsigned short* Wt1  = (unsigned short*)carve((size_t)256 * 512 * 2);

    hipMemsetAsync(d_ws, 0, 256 + (size_t)N * 4, stream);

    detect_kernel<<<1, 256, 0, stream>>>((const int*)ei, flag);
    hist_kernel<<<(E + 255) / 256, 256, 0, stream>>>(ei, flag, cnt, E);
    scan_part<<<NB, 256, 0, stream>>>(cnt, bsum, N);
    scan_top<<<1, 64, 0, stream>>>(bsum, off, NB, N);
    scan_fin<<<NB, 256, 0, stream>>>(cnt, bsum, off, pos, N);
    fill_kernel<<<(E + 255) / 256, 256, 0, stream>>>(ei, flag, pos, adj, E);

    cvt_bf16<<<(N * 128 / 4 + 255) / 256, 256, 0, stream>>>(x, xbf, N * 128 / 4);
    prep_w<<<256, 256, 0, stream>>>(Wl0, Wr0, Wt0, 128);
    prep_w<<<256, 256, 0, stream>>>(Wl1, Wr1, Wt1, 256);

    agg_bf<2><<<(N + 3) / 4, 256, 0, stream>>>(xbf, off, adj, agg0, N);
    sage_mfma<128, true><<<(N + 63) / 64, 256, 0, stream>>>(
        agg0, xbf, Wt0, bl0, bng, bnb, bnm, bnv, hbf, nullptr, N);

    agg_bf<4><<<(N + 3) / 4, 256, 0, stream>>>(hbf, off, adj, agg1, N);
    sage_mfma<256, false><<<(N + 63) / 64, 256, 0, stream>>>(
        agg1, hbf, Wt1, bl1, bng, bnb, bnm, bnv, nullptr, out, N);
}

// Round 11
// 241.344 us; speedup vs baseline: 1.3448x; 1.0251x over previous
//
#include <hip/hip_runtime.h>

#define NN 50000

typedef __bf16 bf16x8 __attribute__((ext_vector_type(8)));
typedef float f32x4 __attribute__((ext_vector_type(4)));

__device__ __forceinline__ unsigned short f2bf(float f) {
    unsigned int u = __builtin_bit_cast(unsigned int, f);
    u += 0x7FFF + ((u >> 16) & 1);  // round-to-nearest-even
    return (unsigned short)(u >> 16);
}
__device__ __forceinline__ float bf2f(unsigned short h) {
    unsigned int u = ((unsigned int)h) << 16;
    return __builtin_bit_cast(float, u);
}
__device__ __forceinline__ void gload16(const void* g, void* l) {
    __builtin_amdgcn_global_load_lds(
        (const __attribute__((address_space(1))) unsigned int*)g,
        (__attribute__((address_space(3))) unsigned int*)l, 16, 0, 0);
}

// ---------------- edge dtype detection ----------------
__global__ void detect_kernel(const int* __restrict__ ei32, int* __restrict__ flag) {
    __shared__ int red[256];
    int tid = threadIdx.x;
    int o = 0;
    for (int i = tid; i < 4096; i += 256) o |= ei32[2 * i + 1];
    red[tid] = o;
    __syncthreads();
    for (int s = 128; s > 0; s >>= 1) {
        if (tid < s) red[tid] |= red[tid + s];
        __syncthreads();
    }
    if (tid == 0) *flag = (red[0] == 0) ? 1 : 0;
}

__device__ __forceinline__ int load_edge(const void* ei, int is64, long long idx) {
    return is64 ? (int)((const long long*)ei)[idx] : ((const int*)ei)[idx];
}

// ---------------- CSR build ----------------
__global__ void hist_kernel(const void* __restrict__ ei, const int* __restrict__ flag,
                            int* __restrict__ cnt, int E) {
    int e = blockIdx.x * blockDim.x + threadIdx.x;
    if (e >= E) return;
    int is64 = *flag;
    int dst = load_edge(ei, is64, (long long)E + e);
    atomicAdd(&cnt[dst], 1);
}

__global__ void scan_part(const int* __restrict__ cnt, int* __restrict__ bsum, int n) {
    __shared__ int s[256];
    const int tid = threadIdx.x;
    const int i0 = blockIdx.x * 1024 + tid * 4;
    int sum = 0;
#pragma unroll
    for (int j = 0; j < 4; ++j) {
        int i = i0 + j;
        if (i < n) sum += cnt[i];
    }
    s[tid] = sum;
    __syncthreads();
    for (int o = 128; o > 0; o >>= 1) {
        if (tid < o) s[tid] += s[tid + o];
        __syncthreads();
    }
    if (tid == 0) bsum[blockIdx.x] = s[0];
}

__global__ void scan_top(int* __restrict__ bsum, int* __restrict__ off, int nb, int n) {
    const int lane = threadIdx.x & 63;
    int mine = (lane < nb) ? bsum[lane] : 0;
    int v = mine;
#pragma unroll
    for (int o = 1; o < 64; o <<= 1) {
        int t = __shfl_up(v, o, 64);
        if (lane >= o) v += t;
    }
    if (lane < nb) bsum[lane] = v - mine;
    if (lane == 63) off[n] = v;
}

__global__ void scan_fin(const int* __restrict__ cnt, const int* __restrict__ bsum,
                         int* __restrict__ off, int* __restrict__ pos, int n) {
    __shared__ int s[256];
    const int tid = threadIdx.x;
    const int i0 = blockIdx.x * 1024 + tid * 4;
    int v[4];
    int sum = 0;
#pragma unroll
    for (int j = 0; j < 4; ++j) {
        int i = i0 + j;
        v[j] = (i < n) ? cnt[i] : 0;
        sum += v[j];
    }
    s[tid] = sum;
    __syncthreads();
    for (int o = 1; o < 256; o <<= 1) {
        int t = 0;
        if (tid >= o) t = s[tid - o];
        __syncthreads();
        s[tid] += t;
        __syncthreads();
    }
    int run = bsum[blockIdx.x] + s[tid] - sum;
#pragma unroll
    for (int j = 0; j < 4; ++j) {
        int i = i0 + j;
        if (i < n) {
            off[i] = run;
            pos[i] = run;
            run += v[j];
        }
    }
}

__global__ void fill_kernel(const void* __restrict__ ei, const int* __restrict__ flag,
                            int* __restrict__ pos, int* __restrict__ adj, int E) {
    int e = blockIdx.x * blockDim.x + threadIdx.x;
    if (e >= E) return;
    int is64 = *flag;
    int src = load_edge(ei, is64, e);
    int dst = load_edge(ei, is64, (long long)E + e);
    int p = atomicAdd(&pos[dst], 1);
    adj[p] = src;
}

// ---------------- f32 -> bf16 convert: row-major + tiled copies ----------------
// Tiled layout (per 64-row block, per 32-k step): [q:4][row:64][frag:8] shorts = 4KB tile.
__global__ void cvt_bf16(const float* __restrict__ in, unsigned short* __restrict__ out,
                         unsigned short* __restrict__ out_t, int n4) {
    int i = blockIdx.x * blockDim.x + threadIdx.x;
    if (i >= n4) return;
    float4 v = ((const float4*)in)[i];
    uint2 o;
    o.x = (unsigned int)f2bf(v.x) | ((unsigned int)f2bf(v.y) << 16);
    o.y = (unsigned int)f2bf(v.z) | ((unsigned int)f2bf(v.w) << 16);
    ((uint2*)out)[i] = o;
    // tiled (F=128, 4 tiles/rowblk)
    int r = i >> 5;            // row
    int kk = (i & 31) * 4;     // feature
    int ts = kk >> 5, q = (kk >> 3) & 3, e = kk & 7;
    size_t idx = ((size_t)(r >> 6) * 4 + ts) * 2048 + q * 512 + (r & 63) * 8 + e;
    *(uint2*)(out_t + idx) = o;
}

// ---------------- weight prep: tiled WtT[step][q][col][8] = bf16([Wl;Wr][k][c]) ------
__global__ void prep_w(const float* __restrict__ Wl, const float* __restrict__ Wr,
                       unsigned short* __restrict__ Wt, int KH) {
    int c = blockIdx.x;  // 0..255
    int KC = 2 * KH;
    for (int k = threadIdx.x; k < KC; k += blockDim.x) {
        float v = (k < KH) ? Wl[(size_t)k * 256 + c] : Wr[(size_t)(k - KH) * 256 + c];
        int ks = k >> 5, q = (k >> 3) & 3, e = k & 7;
        Wt[(size_t)ks * 8192 + q * 2048 + c * 8 + e] = f2bf(v);
    }
}

// ---------------- mean aggregation (MLP=4), writes TILED output ----------------
template <int VPL>  // F = 64*VPL; tiles per rowblk = F/32
__global__ void agg_bf(const unsigned short* __restrict__ feat, const int* __restrict__ off,
                       const int* __restrict__ adj, unsigned short* __restrict__ out_t, int n) {
    int node = blockIdx.x * 4 + (threadIdx.x >> 6);
    if (node >= n) return;
    const int lane = threadIdx.x & 63;
    constexpr int F = 64 * VPL;
    constexpr int NAT = F / 32;
    const int s = off[node], e = off[node + 1];

    float a0[VPL] = {}, a1[VPL] = {}, a2[VPL] = {}, a3[VPL] = {};

    auto addrow = [&](float* acc, int src) {
        const unsigned short* p = feat + (size_t)src * F + lane * VPL;
        if constexpr (VPL == 2) {
            unsigned int v = *(const unsigned int*)p;
            acc[0] += bf2f((unsigned short)(v & 0xffff));
            acc[1] += bf2f((unsigned short)(v >> 16));
        } else {
            uint2 v = *(const uint2*)p;
            acc[0] += bf2f((unsigned short)(v.x & 0xffff));
            acc[1] += bf2f((unsigned short)(v.x >> 16));
            acc[2] += bf2f((unsigned short)(v.y & 0xffff));
            acc[3] += bf2f((unsigned short)(v.y >> 16));
        }
    };

    int j = s;
    for (; j + 4 <= e; j += 4) {
        int i0 = adj[j], i1 = adj[j + 1], i2 = adj[j + 2], i3 = adj[j + 3];
        addrow(a0, i0);
        addrow(a1, i1);
        addrow(a2, i2);
        addrow(a3, i3);
    }
    {
        int rem = e - j;
        if (rem > 0) addrow(a0, adj[j]);
        if (rem > 1) addrow(a1, adj[j + 1]);
        if (rem > 2) addrow(a2, adj[j + 2]);
    }

    int deg = e - s;
    float inv = 1.0f / (float)(deg > 0 ? deg : 1);
#pragma unroll
    for (int k = 0; k < VPL; ++k) a0[k] = (a0[k] + a1[k] + a2[k] + a3[k]) * inv;

    // tiled store
    const int k0 = lane * VPL;
    const int ts = k0 >> 5, q = (k0 >> 3) & 3, e8 = k0 & 7;
    size_t idx = ((size_t)(node >> 6) * NAT + ts) * 2048 + q * 512 + (node & 63) * 8 + e8;
    if constexpr (VPL == 2) {
        unsigned int o = (unsigned int)f2bf(a0[0]) | ((unsigned int)f2bf(a0[1]) << 16);
        *(unsigned int*)(out_t + idx) = o;
    } else {
        uint2 o;
        o.x = (unsigned int)f2bf(a0[0]) | ((unsigned int)f2bf(a0[1]) << 16);
        o.y = (unsigned int)f2bf(a0[2]) | ((unsigned int)f2bf(a0[3]) << 16);
        *(uint2*)(out_t + idx) = o;
    }
}

// ---------------- fused SAGE MFMA GEMM v2: tiled A+B, contiguous gloads, T4 pipeline --
// C[64x256]/block, 4 waves. Per step: 5 contiguous-1KB gload_lds per wave (1 A + 4 B),
// issued 1 step ahead; s_waitcnt vmcnt(5) + raw s_barrier (prefetch stays in flight);
// compute reads LDS only. No __syncthreads in the K-loop.
template <int KH, bool L0>
__global__ void sage_mfma(
    const unsigned short* __restrict__ Aagg_t, const unsigned short* __restrict__ Axin_t,
    const unsigned short* __restrict__ WtT, const float* __restrict__ bl,
    const float* __restrict__ bng, const float* __restrict__ bnb,
    const float* __restrict__ bnm, const float* __restrict__ bnv,
    unsigned short* __restrict__ hout, unsigned short* __restrict__ hout_t,
    float* __restrict__ fout, int n) {
    constexpr int KC = 2 * KH;
    constexpr int NSTEP = KC / 32;
    constexpr int NAT = KH / 32;
    __shared__ __align__(16) unsigned char a_sh[2][4096];
    __shared__ __align__(16) unsigned char b_sh[2][16384];
    __shared__ float red[4][64];
    __shared__ float inv_sh[64];

    const int tid = threadIdx.x;
    const int w = tid >> 6;
    const int l = tid & 63;
    const int g = l >> 4;
    const int li = l & 15;
    const int row0 = blockIdx.x * 64;
    const int blk = blockIdx.x;

    f32x4 acc[4][4];
#pragma unroll
    for (int m = 0; m < 4; ++m)
#pragma unroll
        for (int nn = 0; nn < 4; ++nn) acc[m][nn] = (f32x4)(0.0f);

    // stage step t into buffer buf: all loads contiguous 1KB per wave
    auto stage = [&](int buf, int t) {
        const unsigned short* at =
            (t < NAT) ? Aagg_t + ((size_t)blk * NAT + t) * 2048
                      : Axin_t + ((size_t)blk * NAT + (t - NAT)) * 2048;
        gload16((const char*)at + w * 1024 + l * 16, &a_sh[buf][w * 1024]);
#pragma unroll
        for (int q = 0; q < 4; ++q)
            gload16((const char*)(WtT + (size_t)t * 8192) + q * 4096 + w * 1024 + l * 16,
                    &b_sh[buf][q * 4096 + w * 1024]);
    };

    auto compute = [&](int buf) {
        bf16x8 bfr[4];
#pragma unroll
        for (int nn = 0; nn < 4; ++nn)
            bfr[nn] = __builtin_bit_cast(
                bf16x8, *(const uint4*)&b_sh[buf][g * 4096 + (w * 64 + nn * 16 + li) * 16]);
        bf16x8 afr[4];
#pragma unroll
        for (int m = 0; m < 4; ++m)
            afr[m] = __builtin_bit_cast(bf16x8, *(const uint4*)&a_sh[buf][g * 1024 + (16 * m + li) * 16]);
#pragma unroll
        for (int nn = 0; nn < 4; ++nn)
#pragma unroll
            for (int m = 0; m < 4; ++m)
                acc[m][nn] = __builtin_amdgcn_mfma_f32_16x16x32_bf16(afr[m], bfr[nn], acc[m][nn], 0, 0, 0);
    };

    stage(0, 0);
    __syncthreads();  // prologue: full drain, buf0 ready

    int cur = 0;
    for (int ks = 0; ks < NSTEP - 1; ++ks) {
        stage(cur ^ 1, ks + 1);  // 5 gloads in flight across the barrier
        asm volatile("s_waitcnt vmcnt(5)" ::: "memory");  // my step-ks loads done
        __builtin_amdgcn_sched_barrier(0);
        __builtin_amdgcn_s_barrier();  // => ALL waves' step-ks loads done
        __builtin_amdgcn_sched_barrier(0);
        compute(cur);  // ds_read+MFMA; lgkmcnt retires reads before barrier
        __builtin_amdgcn_s_barrier();  // everyone done reading buf cur
        __builtin_amdgcn_sched_barrier(0);
        cur ^= 1;
    }
    asm volatile("s_waitcnt vmcnt(0)" ::: "memory");
    __builtin_amdgcn_sched_barrier(0);
    __builtin_amdgcn_s_barrier();
    __builtin_amdgcn_sched_barrier(0);
    compute(cur);

    // bias
    float bv[4];
#pragma unroll
    for (int nn = 0; nn < 4; ++nn) bv[nn] = bl[w * 64 + nn * 16 + li];
#pragma unroll
    for (int m = 0; m < 4; ++m)
#pragma unroll
        for (int nn = 0; nn < 4; ++nn)
#pragma unroll
            for (int r = 0; r < 4; ++r) acc[m][nn][r] += bv[nn];

    // row sum-of-squares: in-wave 16-lane reduce, then cross-wave via LDS
    float ssp[4][4];
#pragma unroll
    for (int m = 0; m < 4; ++m)
#pragma unroll
        for (int r = 0; r < 4; ++r) {
            float s = 0.f;
#pragma unroll
            for (int nn = 0; nn < 4; ++nn) s += acc[m][nn][r] * acc[m][nn][r];
#pragma unroll
            for (int mk = 1; mk < 16; mk <<= 1) s += __shfl_xor(s, mk, 64);
            ssp[m][r] = s;
        }
    __syncthreads();
    if (li == 0) {
#pragma unroll
        for (int m = 0; m < 4; ++m)
#pragma unroll
            for (int r = 0; r < 4; ++r) red[w][16 * m + 4 * g + r] = ssp[m][r];
    }
    __syncthreads();
    if (tid < 64) {
        float tot = red[0][tid] + red[1][tid] + red[2][tid] + red[3][tid];
        inv_sh[tid] = 1.0f / fmaxf(sqrtf(tot), 1e-12f);
    }
    __syncthreads();

    float sc[4], sh[4];
    if (L0) {
#pragma unroll
        for (int nn = 0; nn < 4; ++nn) {
            int c = w * 64 + nn * 16 + li;
            float s = bng[c] * rsqrtf(bnv[c] + 1e-5f);
            sc[nn] = s;
            sh[nn] = bnb[c] - bnm[c] * s;
        }
    }
#pragma unroll
    for (int m = 0; m < 4; ++m) {
#pragma unroll
        for (int r = 0; r < 4; ++r) {
            int rl = 16 * m + 4 * g + r;
            int row = row0 + rl;
            if (row < n) {
                float inv = inv_sh[rl];
#pragma unroll
                for (int nn = 0; nn < 4; ++nn) {
                    int c = w * 64 + nn * 16 + li;
                    float v = acc[m][nn][r] * inv;
                    if (L0) {
                        v = fmaxf(v * sc[nn] + sh[nn], 0.f);
                        unsigned short hv = f2bf(v);
                        hout[(size_t)row * 256 + c] = hv;  // row-major (for gather)
                        int ts = c >> 5, q = (c >> 3) & 3, e8 = c & 7;
                        hout_t[((size_t)(row >> 6) * 8 + ts) * 2048 + q * 512 + (row & 63) * 8 + e8] = hv;
                    } else {
                        fout[(size_t)row * 256 + c] = v;
                    }
                }
            }
        }
    }
}

// ---------------- launch ----------------
extern "C" void kernel_launch(void* const* d_in, const int* in_sizes, int n_in,
                              void* d_out, int out_size, void* d_ws, size_t ws_size,
                              hipStream_t stream) {
    const float* x   = (const float*)d_in[0];
    const void*  ei  = d_in[1];
    const float* Wl0 = (const float*)d_in[2];
    const float* bl0 = (const float*)d_in[3];
    const float* Wr0 = (const float*)d_in[4];
    const float* Wl1 = (const float*)d_in[5];
    const float* bl1 = (const float*)d_in[6];
    const float* Wr1 = (const float*)d_in[7];
    const float* bng = (const float*)d_in[8];
    const float* bnb = (const float*)d_in[9];
    const float* bnm = (const float*)d_in[10];
    const float* bnv = (const float*)d_in[11];
    float* out = (float*)d_out;

    const int N = NN;
    const int E = in_sizes[1] / 2;
    const int NB = (N + 1023) / 1024;
    const int NBK = (N + 63) / 64;  // 782 row-blocks

    char* wsp = (char*)d_ws;
    size_t o = 0;
    auto carve = [&](size_t bytes) {
        void* p = wsp + o;
        o = (o + bytes + 255) & ~(size_t)255;
        return p;
    };
    int* flag = (int*)carve(4);
    int* cnt  = (int*)carve((size_t)N * 4);
    int* off  = (int*)carve((size_t)(N + 1) * 4);
    int* pos  = (int*)carve((size_t)N * 4);
    int* bsum = (int*)carve((size_t)NB * 4);
    int* adj  = (int*)carve((size_t)E * 4);
    unsigned short* xbf  = (unsigned short*)carve((size_t)N * 128 * 2);        // row-major x
    // big region: [xbf_t | agg0_t] while layer-0 lives; reused as agg1_t after
    unsigned short* big  = (unsigned short*)carve((size_t)NBK * 8 * 2048 * 2); // 25.6MB
    unsigned short* xbf_t  = big;                          // NBK*4 tiles
    unsigned short* agg0_t = big + (size_t)NBK * 4 * 2048; // NBK*4 tiles
    unsigned short* agg1_t = big;                          // NBK*8 tiles (after L0 done)
    unsigned short* hbf    = (unsigned short*)carve((size_t)N * 256 * 2);          // row-major h
    unsigned short* hbf_t  = (unsigned short*)carve((size_t)NBK * 8 * 2048 * 2);   // tiled h
    unsigned short* Wt0  = (unsigned short*)carve((size_t)8 * 8192 * 2);
    unsigned short* Wt1  = (unsigned short*)carve((size_t)16 * 8192 * 2);

    hipMemsetAsync(d_ws, 0, 256 + (size_t)N * 4, stream);

    detect_kernel<<<1, 256, 0, stream>>>((const int*)ei, flag);
    hist_kernel<<<(E + 255) / 256, 256, 0, stream>>>(ei, flag, cnt, E);
    scan_part<<<NB, 256, 0, stream>>>(cnt, bsum, N);
    scan_top<<<1, 64, 0, stream>>>(bsum, off, NB, N);
    scan_fin<<<NB, 256, 0, stream>>>(cnt, bsum, off, pos, N);
    fill_kernel<<<(E + 255) / 256, 256, 0, stream>>>(ei, flag, pos, adj, E);

    cvt_bf16<<<(N * 128 / 4 + 255) / 256, 256, 0, stream>>>(x, xbf, xbf_t, N * 128 / 4);
    prep_w<<<256, 256, 0, stream>>>(Wl0, Wr0, Wt0, 128);
    prep_w<<<256, 256, 0, stream>>>(Wl1, Wr1, Wt1, 256);

    agg_bf<2><<<(N + 3) / 4, 256, 0, stream>>>(xbf, off, adj, agg0_t, N);
    sage_mfma<128, true><<<NBK, 256, 0, stream>>>(
        agg0_t, xbf_t, Wt0, bl0, bng, bnb, bnm, bnv, hbf, hbf_t, nullptr, N);

    agg_bf<4><<<(N + 3) / 4, 256, 0, stream>>>(hbf, off, adj, agg1_t, N);
    sage_mfma<256, false><<<NBK, 256, 0, stream>>>(
        agg1_t, hbf_t, Wt1, bl1, bng, bnb, bnm, bnv, nullptr, nullptr, out, N);
}

// Round 12
// 233.184 us; speedup vs baseline: 1.3918x; 1.0350x over previous
//
#include <hip/hip_runtime.h>

#define NN 50000

typedef __bf16 bf16x8 __attribute__((ext_vector_type(8)));
typedef float f32x4 __attribute__((ext_vector_type(4)));

__device__ __forceinline__ unsigned short f2bf(float f) {
    unsigned int u = __builtin_bit_cast(unsigned int, f);
    u += 0x7FFF + ((u >> 16) & 1);  // round-to-nearest-even
    return (unsigned short)(u >> 16);
}
__device__ __forceinline__ float bf2f(unsigned short h) {
    unsigned int u = ((unsigned int)h) << 16;
    return __builtin_bit_cast(float, u);
}
__device__ __forceinline__ void gload16(const void* g, void* l) {
    __builtin_amdgcn_global_load_lds(
        (const __attribute__((address_space(1))) unsigned int*)g,
        (__attribute__((address_space(3))) unsigned int*)l, 16, 0, 0);
}

// ---------------- edge dtype detection ----------------
__global__ void detect_kernel(const int* __restrict__ ei32, int* __restrict__ flag) {
    __shared__ int red[256];
    int tid = threadIdx.x;
    int o = 0;
    for (int i = tid; i < 4096; i += 256) o |= ei32[2 * i + 1];
    red[tid] = o;
    __syncthreads();
    for (int s = 128; s > 0; s >>= 1) {
        if (tid < s) red[tid] |= red[tid + s];
        __syncthreads();
    }
    if (tid == 0) *flag = (red[0] == 0) ? 1 : 0;
}

__device__ __forceinline__ int load_edge(const void* ei, int is64, long long idx) {
    return is64 ? (int)((const long long*)ei)[idx] : ((const int*)ei)[idx];
}

// ---------------- CSR build ----------------
__global__ void hist_kernel(const void* __restrict__ ei, const int* __restrict__ flag,
                            int* __restrict__ cnt, int E) {
    int e = blockIdx.x * blockDim.x + threadIdx.x;
    if (e >= E) return;
    int is64 = *flag;
    int dst = load_edge(ei, is64, (long long)E + e);
    atomicAdd(&cnt[dst], 1);
}

__global__ void scan_part(const int* __restrict__ cnt, int* __restrict__ bsum, int n) {
    __shared__ int s[256];
    const int tid = threadIdx.x;
    const int i0 = blockIdx.x * 1024 + tid * 4;
    int sum = 0;
#pragma unroll
    for (int j = 0; j < 4; ++j) {
        int i = i0 + j;
        if (i < n) sum += cnt[i];
    }
    s[tid] = sum;
    __syncthreads();
    for (int o = 128; o > 0; o >>= 1) {
        if (tid < o) s[tid] += s[tid + o];
        __syncthreads();
    }
    if (tid == 0) bsum[blockIdx.x] = s[0];
}

__global__ void scan_top(int* __restrict__ bsum, int* __restrict__ off, int nb, int n) {
    const int lane = threadIdx.x & 63;
    int mine = (lane < nb) ? bsum[lane] : 0;
    int v = mine;
#pragma unroll
    for (int o = 1; o < 64; o <<= 1) {
        int t = __shfl_up(v, o, 64);
        if (lane >= o) v += t;
    }
    if (lane < nb) bsum[lane] = v - mine;
    if (lane == 63) off[n] = v;
}

__global__ void scan_fin(const int* __restrict__ cnt, const int* __restrict__ bsum,
                         int* __restrict__ off, int* __restrict__ pos, int n) {
    __shared__ int s[256];
    const int tid = threadIdx.x;
    const int i0 = blockIdx.x * 1024 + tid * 4;
    int v[4];
    int sum = 0;
#pragma unroll
    for (int j = 0; j < 4; ++j) {
        int i = i0 + j;
        v[j] = (i < n) ? cnt[i] : 0;
        sum += v[j];
    }
    s[tid] = sum;
    __syncthreads();
    for (int o = 1; o < 256; o <<= 1) {
        int t = 0;
        if (tid >= o) t = s[tid - o];
        __syncthreads();
        s[tid] += t;
        __syncthreads();
    }
    int run = bsum[blockIdx.x] + s[tid] - sum;
#pragma unroll
    for (int j = 0; j < 4; ++j) {
        int i = i0 + j;
        if (i < n) {
            off[i] = run;
            pos[i] = run;
            run += v[j];
        }
    }
}

__global__ void fill_kernel(const void* __restrict__ ei, const int* __restrict__ flag,
                            int* __restrict__ pos, int* __restrict__ adj, int E) {
    int e = blockIdx.x * blockDim.x + threadIdx.x;
    if (e >= E) return;
    int is64 = *flag;
    int src = load_edge(ei, is64, e);
    int dst = load_edge(ei, is64, (long long)E + e);
    int p = atomicAdd(&pos[dst], 1);
    adj[p] = src;
}

// ---------------- f32 -> bf16 convert: row-major + tiled copies ----------------
// Tiled layout (per 64-row block, per 32-k step): [q:4][row:64][frag:8] shorts = 4KB tile.
__global__ void cvt_bf16(const float* __restrict__ in, unsigned short* __restrict__ out,
                         unsigned short* __restrict__ out_t, int n4) {
    int i = blockIdx.x * blockDim.x + threadIdx.x;
    if (i >= n4) return;
    float4 v = ((const float4*)in)[i];
    uint2 o;
    o.x = (unsigned int)f2bf(v.x) | ((unsigned int)f2bf(v.y) << 16);
    o.y = (unsigned int)f2bf(v.z) | ((unsigned int)f2bf(v.w) << 16);
    ((uint2*)out)[i] = o;
    // tiled (F=128, 4 tiles/rowblk)
    int r = i >> 5;            // row
    int kk = (i & 31) * 4;     // feature
    int ts = kk >> 5, q = (kk >> 3) & 3, e = kk & 7;
    size_t idx = ((size_t)(r >> 6) * 4 + ts) * 2048 + q * 512 + (r & 63) * 8 + e;
    *(uint2*)(out_t + idx) = o;
}

// ---------------- weight prep: tiled WtT[step][q][col][8] = bf16([Wl;Wr][k][c]) ------
__global__ void prep_w(const float* __restrict__ Wl, const float* __restrict__ Wr,
                       unsigned short* __restrict__ Wt, int KH) {
    int c = blockIdx.x;  // 0..255
    int KC = 2 * KH;
    for (int k = threadIdx.x; k < KC; k += blockDim.x) {
        float v = (k < KH) ? Wl[(size_t)k * 256 + c] : Wr[(size_t)(k - KH) * 256 + c];
        int ks = k >> 5, q = (k >> 3) & 3, e = k & 7;
        Wt[(size_t)ks * 8192 + q * 2048 + c * 8 + e] = f2bf(v);
    }
}

// ---------------- mean aggregation v2: HALF-WAVE per node ----------------
// 32 lanes cover the full F-dim row (L0: uint2/lane, L1: uint4/lane), so one wave
// processes 2 nodes concurrently: per-node loop iterations, adj loads and address
// arithmetic halve vs wave-per-node. x4 independent-accumulator unroll (MLP=4).
// Output written TILED for the GEMM's contiguous global_load_lds staging.
template <int F>  // 128 (uint2/lane) or 256 (uint4/lane)
__global__ void agg_bf(const unsigned short* __restrict__ feat, const int* __restrict__ off,
                       const int* __restrict__ adj, unsigned short* __restrict__ out_t, int n) {
    constexpr int VPL = F / 32;  // feats per lane: 4 or 8
    constexpr int NAT = F / 32;  // tiles per rowblock: 4 or 8
    int node = blockIdx.x * 8 + (threadIdx.x >> 5);
    if (node >= n) return;
    const int lane = threadIdx.x & 31;
    const int s = off[node], e = off[node + 1];

    float a0[VPL] = {}, a1[VPL] = {}, a2[VPL] = {}, a3[VPL] = {};

    auto addrow = [&](float* acc, int src) {
        const unsigned short* p = feat + (size_t)src * F + lane * VPL;
        if constexpr (VPL == 4) {
            uint2 v = *(const uint2*)p;
            acc[0] += bf2f((unsigned short)(v.x & 0xffff));
            acc[1] += bf2f((unsigned short)(v.x >> 16));
            acc[2] += bf2f((unsigned short)(v.y & 0xffff));
            acc[3] += bf2f((unsigned short)(v.y >> 16));
        } else {
            uint4 v = *(const uint4*)p;
            acc[0] += bf2f((unsigned short)(v.x & 0xffff));
            acc[1] += bf2f((unsigned short)(v.x >> 16));
            acc[2] += bf2f((unsigned short)(v.y & 0xffff));
            acc[3] += bf2f((unsigned short)(v.y >> 16));
            acc[4] += bf2f((unsigned short)(v.z & 0xffff));
            acc[5] += bf2f((unsigned short)(v.z >> 16));
            acc[6] += bf2f((unsigned short)(v.w & 0xffff));
            acc[7] += bf2f((unsigned short)(v.w >> 16));
        }
    };

    int j = s;
    for (; j + 4 <= e; j += 4) {
        int i0 = adj[j], i1 = adj[j + 1], i2 = adj[j + 2], i3 = adj[j + 3];
        addrow(a0, i0);
        addrow(a1, i1);
        addrow(a2, i2);
        addrow(a3, i3);
    }
    {
        int rem = e - j;
        if (rem > 0) addrow(a0, adj[j]);
        if (rem > 1) addrow(a1, adj[j + 1]);
        if (rem > 2) addrow(a2, adj[j + 2]);
    }

    int deg = e - s;
    float inv = 1.0f / (float)(deg > 0 ? deg : 1);
#pragma unroll
    for (int k = 0; k < VPL; ++k) a0[k] = (a0[k] + a1[k] + a2[k] + a3[k]) * inv;

    // tiled store
    const int k0 = lane * VPL;
    const int ts = k0 >> 5, q = (k0 >> 3) & 3, e8 = k0 & 7;
    size_t idx = ((size_t)(node >> 6) * NAT + ts) * 2048 + q * 512 + (node & 63) * 8 + e8;
    if constexpr (VPL == 4) {
        uint2 o;
        o.x = (unsigned int)f2bf(a0[0]) | ((unsigned int)f2bf(a0[1]) << 16);
        o.y = (unsigned int)f2bf(a0[2]) | ((unsigned int)f2bf(a0[3]) << 16);
        *(uint2*)(out_t + idx) = o;
    } else {
        uint4 o;
        o.x = (unsigned int)f2bf(a0[0]) | ((unsigned int)f2bf(a0[1]) << 16);
        o.y = (unsigned int)f2bf(a0[2]) | ((unsigned int)f2bf(a0[3]) << 16);
        o.z = (unsigned int)f2bf(a0[4]) | ((unsigned int)f2bf(a0[5]) << 16);
        o.w = (unsigned int)f2bf(a0[6]) | ((unsigned int)f2bf(a0[7]) << 16);
        *(uint4*)(out_t + idx) = o;
    }
}

// ---------------- fused SAGE MFMA GEMM v2: tiled A+B, contiguous gloads, T4 pipeline --
// C[64x256]/block, 4 waves. Per step: 5 contiguous-1KB gload_lds per wave (1 A + 4 B),
// issued 1 step ahead; s_waitcnt vmcnt(5) + raw s_barrier (prefetch stays in flight);
// compute reads LDS only. No __syncthreads in the K-loop.
template <int KH, bool L0>
__global__ void sage_mfma(
    const unsigned short* __restrict__ Aagg_t, const unsigned short* __restrict__ Axin_t,
    const unsigned short* __restrict__ WtT, const float* __restrict__ bl,
    const float* __restrict__ bng, const float* __restrict__ bnb,
    const float* __restrict__ bnm, const float* __restrict__ bnv,
    unsigned short* __restrict__ hout, unsigned short* __restrict__ hout_t,
    float* __restrict__ fout, int n) {
    constexpr int KC = 2 * KH;
    constexpr int NSTEP = KC / 32;
    constexpr int NAT = KH / 32;
    __shared__ __align__(16) unsigned char a_sh[2][4096];
    __shared__ __align__(16) unsigned char b_sh[2][16384];
    __shared__ float red[4][64];
    __shared__ float inv_sh[64];

    const int tid = threadIdx.x;
    const int w = tid >> 6;
    const int l = tid & 63;
    const int g = l >> 4;
    const int li = l & 15;
    const int row0 = blockIdx.x * 64;
    const int blk = blockIdx.x;

    f32x4 acc[4][4];
#pragma unroll
    for (int m = 0; m < 4; ++m)
#pragma unroll
        for (int nn = 0; nn < 4; ++nn) acc[m][nn] = (f32x4)(0.0f);

    // stage step t into buffer buf: all loads contiguous 1KB per wave
    auto stage = [&](int buf, int t) {
        const unsigned short* at =
            (t < NAT) ? Aagg_t + ((size_t)blk * NAT + t) * 2048
                      : Axin_t + ((size_t)blk * NAT + (t - NAT)) * 2048;
        gload16((const char*)at + w * 1024 + l * 16, &a_sh[buf][w * 1024]);
#pragma unroll
        for (int q = 0; q < 4; ++q)
            gload16((const char*)(WtT + (size_t)t * 8192) + q * 4096 + w * 1024 + l * 16,
                    &b_sh[buf][q * 4096 + w * 1024]);
    };

    auto compute = [&](int buf) {
        bf16x8 bfr[4];
#pragma unroll
        for (int nn = 0; nn < 4; ++nn)
            bfr[nn] = __builtin_bit_cast(
                bf16x8, *(const uint4*)&b_sh[buf][g * 4096 + (w * 64 + nn * 16 + li) * 16]);
        bf16x8 afr[4];
#pragma unroll
        for (int m = 0; m < 4; ++m)
            afr[m] = __builtin_bit_cast(bf16x8, *(const uint4*)&a_sh[buf][g * 1024 + (16 * m + li) * 16]);
#pragma unroll
        for (int nn = 0; nn < 4; ++nn)
#pragma unroll
            for (int m = 0; m < 4; ++m)
                acc[m][nn] = __builtin_amdgcn_mfma_f32_16x16x32_bf16(afr[m], bfr[nn], acc[m][nn], 0, 0, 0);
    };

    stage(0, 0);
    __syncthreads();  // prologue: full drain, buf0 ready

    int cur = 0;
    for (int ks = 0; ks < NSTEP - 1; ++ks) {
        stage(cur ^ 1, ks + 1);  // 5 gloads in flight across the barrier
        asm volatile("s_waitcnt vmcnt(5)" ::: "memory");  // my step-ks loads done
        __builtin_amdgcn_sched_barrier(0);
        __builtin_amdgcn_s_barrier();  // => ALL waves' step-ks loads done
        __builtin_amdgcn_sched_barrier(0);
        compute(cur);  // ds_read+MFMA; lgkmcnt retires reads before barrier
        __builtin_amdgcn_s_barrier();  // everyone done reading buf cur
        __builtin_amdgcn_sched_barrier(0);
        cur ^= 1;
    }
    asm volatile("s_waitcnt vmcnt(0)" ::: "memory");
    __builtin_amdgcn_sched_barrier(0);
    __builtin_amdgcn_s_barrier();
    __builtin_amdgcn_sched_barrier(0);
    compute(cur);

    // bias
    float bv[4];
#pragma unroll
    for (int nn = 0; nn < 4; ++nn) bv[nn] = bl[w * 64 + nn * 16 + li];
#pragma unroll
    for (int m = 0; m < 4; ++m)
#pragma unroll
        for (int nn = 0; nn < 4; ++nn)
#pragma unroll
            for (int r = 0; r < 4; ++r) acc[m][nn][r] += bv[nn];

    // row sum-of-squares: in-wave 16-lane reduce, then cross-wave via LDS
    float ssp[4][4];
#pragma unroll
    for (int m = 0; m < 4; ++m)
#pragma unroll
        for (int r = 0; r < 4; ++r) {
            float s = 0.f;
#pragma unroll
            for (int nn = 0; nn < 4; ++nn) s += acc[m][nn][r] * acc[m][nn][r];
#pragma unroll
            for (int mk = 1; mk < 16; mk <<= 1) s += __shfl_xor(s, mk, 64);
            ssp[m][r] = s;
        }
    __syncthreads();
    if (li == 0) {
#pragma unroll
        for (int m = 0; m < 4; ++m)
#pragma unroll
            for (int r = 0; r < 4; ++r) red[w][16 * m + 4 * g + r] = ssp[m][r];
    }
    __syncthreads();
    if (tid < 64) {
        float tot = red[0][tid] + red[1][tid] + red[2][tid] + red[3][tid];
        inv_sh[tid] = 1.0f / fmaxf(sqrtf(tot), 1e-12f);
    }
    __syncthreads();

    float sc[4], sh[4];
    if (L0) {
#pragma unroll
        for (int nn = 0; nn < 4; ++nn) {
            int c = w * 64 + nn * 16 + li;
            float s = bng[c] * rsqrtf(bnv[c] + 1e-5f);
            sc[nn] = s;
            sh[nn] = bnb[c] - bnm[c] * s;
        }
    }
#pragma unroll
    for (int m = 0; m < 4; ++m) {
#pragma unroll
        for (int r = 0; r < 4; ++r) {
            int rl = 16 * m + 4 * g + r;
            int row = row0 + rl;
            if (row < n) {
                float inv = inv_sh[rl];
#pragma unroll
                for (int nn = 0; nn < 4; ++nn) {
                    int c = w * 64 + nn * 16 + li;
                    float v = acc[m][nn][r] * inv;
                    if (L0) {
                        v = fmaxf(v * sc[nn] + sh[nn], 0.f);
                        unsigned short hv = f2bf(v);
                        hout[(size_t)row * 256 + c] = hv;  // row-major (for gather)
                        int ts = c >> 5, q = (c >> 3) & 3, e8 = c & 7;
                        hout_t[((size_t)(row >> 6) * 8 + ts) * 2048 + q * 512 + (row & 63) * 8 + e8] = hv;
                    } else {
                        fout[(size_t)row * 256 + c] = v;
                    }
                }
            }
        }
    }
}

// ---------------- launch ----------------
extern "C" void kernel_launch(void* const* d_in, const int* in_sizes, int n_in,
                              void* d_out, int out_size, void* d_ws, size_t ws_size,
                              hipStream_t stream) {
    const float* x   = (const float*)d_in[0];
    const void*  ei  = d_in[1];
    const float* Wl0 = (const float*)d_in[2];
    const float* bl0 = (const float*)d_in[3];
    const float* Wr0 = (const float*)d_in[4];
    const float* Wl1 = (const float*)d_in[5];
    const float* bl1 = (const float*)d_in[6];
    const float* Wr1 = (const float*)d_in[7];
    const float* bng = (const float*)d_in[8];
    const float* bnb = (const float*)d_in[9];
    const float* bnm = (const float*)d_in[10];
    const float* bnv = (const float*)d_in[11];
    float* out = (float*)d_out;

    const int N = NN;
    const int E = in_sizes[1] / 2;
    const int NB = (N + 1023) / 1024;
    const int NBK = (N + 63) / 64;  // 782 row-blocks

    char* wsp = (char*)d_ws;
    size_t o = 0;
    auto carve = [&](size_t bytes) {
        void* p = wsp + o;
        o = (o + bytes + 255) & ~(size_t)255;
        return p;
    };
    int* flag = (int*)carve(4);
    int* cnt  = (int*)carve((size_t)N * 4);
    int* off  = (int*)carve((size_t)(N + 1) * 4);
    int* pos  = (int*)carve((size_t)N * 4);
    int* bsum = (int*)carve((size_t)NB * 4);
    int* adj  = (int*)carve((size_t)E * 4);
    unsigned short* xbf  = (unsigned short*)carve((size_t)N * 128 * 2);        // row-major x
    // big region: [xbf_t | agg0_t] while layer-0 lives; reused as agg1_t after
    unsigned short* big  = (unsigned short*)carve((size_t)NBK * 8 * 2048 * 2); // 25.6MB
    unsigned short* xbf_t  = big;                          // NBK*4 tiles
    unsigned short* agg0_t = big + (size_t)NBK * 4 * 2048; // NBK*4 tiles
    unsigned short* agg1_t = big;                          // NBK*8 tiles (after L0 done)
    unsigned short* hbf    = (unsigned short*)carve((size_t)N * 256 * 2);          // row-major h
    unsigned short* hbf_t  = (unsigned short*)carve((size_t)NBK * 8 * 2048 * 2);   // tiled h
    unsigned short* Wt0  = (unsigned short*)carve((size_t)8 * 8192 * 2);
    unsigned short* Wt1  = (unsigned short*)carve((size_t)16 * 8192 * 2);

    hipMemsetAsync(d_ws, 0, 256 + (size_t)N * 4, stream);

    detect_kernel<<<1, 256, 0, stream>>>((const int*)ei, flag);
    hist_kernel<<<(E + 255) / 256, 256, 0, stream>>>(ei, flag, cnt, E);
    scan_part<<<NB, 256, 0, stream>>>(cnt, bsum, N);
    scan_top<<<1, 64, 0, stream>>>(bsum, off, NB, N);
    scan_fin<<<NB, 256, 0, stream>>>(cnt, bsum, off, pos, N);
    fill_kernel<<<(E + 255) / 256, 256, 0, stream>>>(ei, flag, pos, adj, E);

    cvt_bf16<<<(N * 128 / 4 + 255) / 256, 256, 0, stream>>>(x, xbf, xbf_t, N * 128 / 4);
    prep_w<<<256, 256, 0, stream>>>(Wl0, Wr0, Wt0, 128);
    prep_w<<<256, 256, 0, stream>>>(Wl1, Wr1, Wt1, 256);

    agg_bf<128><<<(N + 7) / 8, 256, 0, stream>>>(xbf, off, adj, agg0_t, N);
    sage_mfma<128, true><<<NBK, 256, 0, stream>>>(
        agg0_t, xbf_t, Wt0, bl0, bng, bnb, bnm, bnv, hbf, hbf_t, nullptr, N);

    agg_bf<256><<<(N + 7) / 8, 256, 0, stream>>>(hbf, off, adj, agg1_t, N);
    sage_mfma<256, false><<<NBK, 256, 0, stream>>>(
        agg1_t, hbf_t, Wt1, bl1, bng, bnb, bnm, bnv, nullptr, nullptr, out, N);
}